// Round 1
// baseline (822.034 us; speedup 1.0000x reference)
//
#include <hip/hip_runtime.h>
#include <cstdint>
#include <cstddef>

#define NUM_NODES 200000
#define NODE_DIM  256
#define MSG_DIM   685
#define NUM_UPD   65536
#define KPAD      960     // 685 + 256 = 941 -> pad to 15*64
#define NOUT      1024    // 256 dims * 4 gates, interleaved per 16-col MFMA tile

typedef __bf16 bf16;
typedef bf16  bf16x8 __attribute__((ext_vector_type(8)));
typedef float f32x4  __attribute__((ext_vector_type(4)));

__device__ inline void async_load16(const void* g, void* l) {
    __builtin_amdgcn_global_load_lds(
        (const __attribute__((address_space(1))) void*)g,
        (__attribute__((address_space(3))) void*)l,
        16, 0, 0);
}

__device__ inline float sigmoidf_(float x) { return 1.0f / (1.0f + __expf(-x)); }
__device__ inline float tanhf_(float x)    { return 1.0f - 2.0f / (1.0f + __expf(2.0f * x)); }

// ---- last-write-wins resolution ---------------------------------------------
__global__ void k_winner(const int* __restrict__ idx, int* __restrict__ winner) {
    int u = blockIdx.x * 256 + threadIdx.x;
    atomicMax(&winner[idx[u]], u);
}

// ---- copy-through of untouched rows -----------------------------------------
__global__ void k_copy(const float* __restrict__ mem, const int* __restrict__ winner,
                       float* __restrict__ out) {
    int row = blockIdx.x * 4 + (threadIdx.x >> 6);   // one wave per row
    int c   = threadIdx.x & 63;                      // 64 float4 per row
    if (winner[row] >= 0) return;                    // epilogue will write it
    const float4* src = (const float4*)(mem + (size_t)row * NODE_DIM);
    float4*       dst = (float4*)(out + (size_t)row * NODE_DIM);
    dst[c] = src[c];
}

// ---- build gate-interleaved combined weight Wc [NOUT x KPAD] (B^T layout) ----
// out col n: ntile=n>>4, gate=ntile&3, dim=(ntile>>2)*16 + (n&15)
// k < 685      : msg part  (W_ih rows gate*256+dim; gate 3 -> 0)
// 685 <= k <941: h part    (W_hh rows gate*256+dim for gates 0,1; gate3=n_h; gate2 -> 0)
__global__ void k_prep_wc(const float* __restrict__ W_ih, const float* __restrict__ W_hh,
                          bf16* __restrict__ Wc) {
    int n = blockIdx.x;
    int ntile = n >> 4, cc = n & 15;
    int gate = ntile & 3;
    int dim  = (ntile >> 2) * 16 + cc;
    for (int i = 0; i < 4; i++) {
        int k = i * 256 + (int)threadIdx.x;
        if (k >= KPAD) break;
        float v = 0.f;
        if (k < MSG_DIM) {
            if (gate == 0)      v = W_ih[(size_t)dim * MSG_DIM + k];
            else if (gate == 1) v = W_ih[(size_t)(256 + dim) * MSG_DIM + k];
            else if (gate == 2) v = W_ih[(size_t)(512 + dim) * MSG_DIM + k];
        } else if (k < MSG_DIM + NODE_DIM) {
            int j = k - MSG_DIM;
            if (gate == 0)      v = W_hh[(size_t)dim * NODE_DIM + j];
            else if (gate == 1) v = W_hh[(size_t)(256 + dim) * NODE_DIM + j];
            else if (gate == 3) v = W_hh[(size_t)(512 + dim) * NODE_DIM + j];
        }
        Wc[(size_t)n * KPAD + k] = (bf16)v;
    }
}

// ---- build X = [messages | gathered h | 0-pad] in bf16 [NUM_UPD x KPAD] ------
__global__ void k_prep_x(const float* __restrict__ msgs, const float* __restrict__ mem,
                         const int* __restrict__ idx, bf16* __restrict__ X) {
    int u = blockIdx.x;
    int node = idx[u];
    const float* mrow = msgs + (size_t)u * MSG_DIM;
    const float* hrow = mem + (size_t)node * NODE_DIM;
    bf16* xrow = X + (size_t)u * KPAD;
    for (int k = threadIdx.x; k < KPAD; k += 256) {
        float v = 0.f;
        if (k < MSG_DIM)                  v = mrow[k];
        else if (k < MSG_DIM + NODE_DIM)  v = hrow[k - MSG_DIM];
        xrow[k] = (bf16)v;
    }
}

// ---- fused GEMM (X * Wc^T) + GRU epilogue + guarded scatter ------------------
// BM=128 BN=128 BK=64, 4 waves (2x2), each wave 64x64 via 4x4 mfma_16x16x32_bf16
__global__ __launch_bounds__(256) void k_gemm(
        const bf16* __restrict__ X, const bf16* __restrict__ Wc,
        const float* __restrict__ mem, const int* __restrict__ idx,
        const int* __restrict__ winner,
        const float* __restrict__ b_ih, const float* __restrict__ b_hh,
        float* __restrict__ out) {
    __shared__ bf16 As[128 * 64];
    __shared__ bf16 Bs[128 * 64];

    const int tid = threadIdx.x;
    const int w = tid >> 6, l = tid & 63;
    const int wr = w >> 1, wc = w & 1;
    const int quad = l >> 4, c = l & 15;

    const int bn = blockIdx.x & 7;      // consecutive blocks share the A panel
    const int bm = blockIdx.x >> 3;

    f32x4 acc[4][4];
    #pragma unroll
    for (int i = 0; i < 4; i++)
        #pragma unroll
        for (int j = 0; j < 4; j++) acc[i][j] = (f32x4){0.f, 0.f, 0.f, 0.f};

    const int flatr = (tid * 8) >> 6;   // staging: 256 lanes x 16B x 4 issues = 16KB tile
    const int flatc = (tid * 8) & 63;
    const bf16* gA = X  + (size_t)(bm * 128) * KPAD;
    const bf16* gB = Wc + (size_t)(bn * 128) * KPAD;

    for (int kt = 0; kt < KPAD / 64; kt++) {
        const int k0 = kt * 64;
        #pragma unroll
        for (int j = 0; j < 4; j++) {
            int r = j * 32 + flatr;
            async_load16(gA + (size_t)r * KPAD + k0 + flatc, (void*)(As + j * 2048 + w * 512));
        }
        #pragma unroll
        for (int j = 0; j < 4; j++) {
            int r = j * 32 + flatr;
            async_load16(gB + (size_t)r * KPAD + k0 + flatc, (void*)(Bs + j * 2048 + w * 512));
        }
        __syncthreads();
        #pragma unroll
        for (int kk = 0; kk < 2; kk++) {
            bf16x8 a[4], b[4];
            #pragma unroll
            for (int mi = 0; mi < 4; mi++)
                a[mi] = *(const bf16x8*)&As[(wr * 64 + mi * 16 + c) * 64 + kk * 32 + quad * 8];
            #pragma unroll
            for (int ni = 0; ni < 4; ni++)
                b[ni] = *(const bf16x8*)&Bs[(wc * 64 + ni * 16 + c) * 64 + kk * 32 + quad * 8];
            #pragma unroll
            for (int mi = 0; mi < 4; mi++)
                #pragma unroll
                for (int ni = 0; ni < 4; ni++)
                    acc[mi][ni] = __builtin_amdgcn_mfma_f32_16x16x32_bf16(a[mi], b[ni], acc[mi][ni], 0, 0, 0);
        }
        __syncthreads();
    }

    // epilogue: lane holds, for each (mi,v)-row, all 4 gates of hidden dim `dim`
    const int dim = (bn * 2 + wc) * 16 + c;
    const float br  = b_ih[dim]       + b_hh[dim];
    const float bz  = b_ih[256 + dim] + b_hh[256 + dim];
    const float bin = b_ih[512 + dim];
    const float bhn = b_hh[512 + dim];

    #pragma unroll
    for (int mi = 0; mi < 4; mi++) {
        #pragma unroll
        for (int v = 0; v < 4; v++) {
            int u = bm * 128 + wr * 64 + mi * 16 + quad * 4 + v;
            int node = idx[u];
            if (winner[node] != u) continue;   // only last update for this node writes
            float r  = sigmoidf_(acc[mi][0][v] + br);
            float z  = sigmoidf_(acc[mi][1][v] + bz);
            float nn = tanhf_(acc[mi][2][v] + bin + r * (acc[mi][3][v] + bhn));
            float h  = mem[(size_t)node * NODE_DIM + dim];
            out[(size_t)node * NODE_DIM + dim] = (1.f - z) * nn + z * h;
        }
    }
}

extern "C" void kernel_launch(void* const* d_in, const int* in_sizes, int n_in,
                              void* d_out, int out_size, void* d_ws, size_t ws_size,
                              hipStream_t stream) {
    const float* memory   = (const float*)d_in[0];
    const float* messages = (const float*)d_in[1];
    const int*   node_idx = (const int*)d_in[2];
    const float* W_ih     = (const float*)d_in[3];
    const float* W_hh     = (const float*)d_in[4];
    const float* b_ih     = (const float*)d_in[5];
    const float* b_hh     = (const float*)d_in[6];
    float* out = (float*)d_out;

    char* ws = (char*)d_ws;
    bf16* X  = (bf16*)ws;                                           // 65536*960*2 = 120 MiB
    bf16* Wc = (bf16*)(ws + (size_t)NUM_UPD * KPAD * 2);            // 1024*960*2  = 1.9 MiB
    int* winner = (int*)(ws + (size_t)NUM_UPD * KPAD * 2 + (size_t)NOUT * KPAD * 2);

    hipMemsetAsync(winner, 0xFF, NUM_NODES * sizeof(int), stream);  // all -1
    k_winner <<<NUM_UPD / 256, 256, 0, stream>>>(node_idx, winner);
    k_copy   <<<NUM_NODES / 4, 256, 0, stream>>>(memory, winner, out);
    k_prep_wc<<<NOUT, 256, 0, stream>>>(W_ih, W_hh, Wc);
    k_prep_x <<<NUM_UPD, 256, 0, stream>>>(messages, memory, node_idx, X);
    k_gemm   <<<(NUM_UPD / 128) * (NOUT / 128), 256, 0, stream>>>(
        X, Wc, memory, node_idx, winner, b_ih, b_hh, out);
}